// Round 10
// baseline (323.728 us; speedup 1.0000x reference)
//
#include <hip/hip_runtime.h>
#include <cstddef>

#define NN 100000
#define NE 600000
#define HID 128

typedef _Float16 half8 __attribute__((ext_vector_type(8)));
typedef _Float16 half2v __attribute__((ext_vector_type(2)));
typedef float f32x4 __attribute__((ext_vector_type(4)));

union H8 { _Float16 h[8]; half2v p[4]; uint4 u; half8 v; };

// shared accumulate helper: accf[0..7] += 8 f16 lanes of hh
__device__ __forceinline__ void acc8(const H8& hh, float* accf) {
#if __has_builtin(__builtin_amdgcn_fdot2)
    const half2v selx = {(_Float16)1.0f, (_Float16)0.0f};
    const half2v sely = {(_Float16)0.0f, (_Float16)1.0f};
    #pragma unroll
    for (int p = 0; p < 4; ++p) {
        accf[2*p]   = __builtin_amdgcn_fdot2(hh.p[p], selx, accf[2*p],   false);
        accf[2*p+1] = __builtin_amdgcn_fdot2(hh.p[p], sely, accf[2*p+1], false);
    }
#else
    #pragma unroll
    for (int j = 0; j < 8; ++j) accf[j] += (float)hh.h[j];
#endif
}

// ---------------------------------------------------------------- degree (int)
__global__ void k_degi(const int* __restrict__ col, int* __restrict__ degi, int E) {
    int e = blockIdx.x * blockDim.x + threadIdx.x;
    if (e < E) atomicAdd(&degi[col[e]], 1);
}

// ---------------------------------------------------------------- W -> WT f16
__global__ void k_wprep(const float* __restrict__ W1, const float* __restrict__ W2,
                        const float* __restrict__ W3, _Float16* __restrict__ wt) {
    int b = blockIdx.x;            // 0..383
    int layer = b >> 7, k = b & 127;
    const float* W = layer == 0 ? W1 : (layer == 1 ? W2 : W3);
    int c = threadIdx.x;           // 0..127
    wt[((size_t)layer << 14) + c * 128 + k] = (_Float16)W[k * 128 + c];
}

// ---------------------------------------------------------------- prefix scan
__global__ void k_blocksum(const int* __restrict__ degi, float* __restrict__ dinv,
                           int* __restrict__ bsum, int N) {
    __shared__ int sh[256];
    int i = blockIdx.x * 256 + threadIdx.x;
    int v = i < N ? degi[i] : 0;
    if (i < N) dinv[i] = v > 0 ? rsqrtf((float)v) : 0.0f;
    sh[threadIdx.x] = v;
    __syncthreads();
    for (int s = 128; s > 0; s >>= 1) {
        if (threadIdx.x < s) sh[threadIdx.x] += sh[threadIdx.x + s];
        __syncthreads();
    }
    if (threadIdx.x == 0) bsum[blockIdx.x] = sh[0];
}

__global__ void k_scan_bsum(int* __restrict__ bsum, int nb) {
    __shared__ int sh[512];
    int tid = threadIdx.x;
    int v = (tid < nb) ? bsum[tid] : 0;
    sh[tid] = v;
    __syncthreads();
    #pragma unroll
    for (int s = 1; s < 512; s <<= 1) {
        int t = (tid >= s) ? sh[tid - s] : 0;
        __syncthreads();
        sh[tid] += t;
        __syncthreads();
    }
    if (tid < nb) bsum[tid] = sh[tid] - v;   // exclusive
}

__global__ void k_scan_apply(const int* __restrict__ degi, const int* __restrict__ bsum,
                             int* __restrict__ rowptr, int* __restrict__ cursor, int N) {
    __shared__ int sh[256];
    int i = blockIdx.x * 256 + threadIdx.x;
    int v = (i < N) ? degi[i] : 0;
    sh[threadIdx.x] = v;
    __syncthreads();
    #pragma unroll
    for (int s = 1; s < 256; s <<= 1) {
        int t = (threadIdx.x >= s) ? sh[threadIdx.x - s] : 0;
        __syncthreads();
        sh[threadIdx.x] += t;
        __syncthreads();
    }
    if (i < N) {
        int excl = bsum[blockIdx.x] + sh[threadIdx.x] - v;
        rowptr[i] = excl;
        cursor[i] = excl;
        if (i == N - 1) rowptr[N] = bsum[blockIdx.x] + sh[threadIdx.x];
    }
}

// csr_off stores BYTE offset of the source row (src * HID * 2, fits int32)
__global__ void k_fill_csr(const int* __restrict__ row, const int* __restrict__ col,
                           int* __restrict__ cursor, int* __restrict__ csr_off, int E) {
    int e = blockIdx.x * blockDim.x + threadIdx.x;
    if (e >= E) return;
    int r = row[e], c = col[e];
    int pos = atomicAdd(&cursor[c], 1);
    csr_off[pos] = r * (HID * 2);
}

// ---------------------------------------------------------------- MFMA GEMM (layer 1)
// H[r] (f16) = dinv[r] * (A[r] @ W)
__global__ __launch_bounds__(256, 2) void k_gemm(
    const float* __restrict__ A, const _Float16* __restrict__ WT,
    const float* __restrict__ dinv, _Float16* __restrict__ H, int nrows)
{
    __shared__ _Float16 asl[128 * 128];   // 32 KB
    __shared__ _Float16 wsl[128 * 128];   // 32 KB
    const int tid  = threadIdx.x;
    const int lane = tid & 63;
    const int w    = tid >> 6;
    const int wm   = w >> 1, wn = w & 1;
    const int ln15 = lane & 15;
    const int hi   = lane >> 4;           // 0..3
    const int row0 = blockIdx.x * 128;

    #pragma unroll
    for (int i = 0; i < 8; ++i) {
        int g = i * 256 + tid;
        int c = g >> 4, k8 = (g & 15) << 3;
        uint4 wv = *(const uint4*)(WT + c * 128 + k8);
        *(uint4*)&wsl[c * 128 + (k8 ^ ((c & 7) << 3))] = wv;
    }
    #pragma unroll
    for (int i = 0; i < 8; ++i) {
        int g = i * 256 + tid;
        int r = g >> 4, c8 = (g & 15) << 3;
        int gr = row0 + r; if (gr >= nrows) gr = nrows - 1;
        const float4* src = (const float4*)(A + (size_t)gr * HID + c8);
        float4 v0 = src[0], v1 = src[1];
        H8 o;
        o.h[0] = (_Float16)v0.x; o.h[1] = (_Float16)v0.y;
        o.h[2] = (_Float16)v0.z; o.h[3] = (_Float16)v0.w;
        o.h[4] = (_Float16)v1.x; o.h[5] = (_Float16)v1.y;
        o.h[6] = (_Float16)v1.z; o.h[7] = (_Float16)v1.w;
        *(uint4*)&asl[r * 128 + (c8 ^ ((r & 7) << 3))] = o.u;
    }
    __syncthreads();

    f32x4 acc[4][4];
    #pragma unroll
    for (int i = 0; i < 4; ++i)
        #pragma unroll
        for (int j = 0; j < 4; ++j) {
            acc[i][j][0] = 0.0f; acc[i][j][1] = 0.0f;
            acc[i][j][2] = 0.0f; acc[i][j][3] = 0.0f;
        }

    #pragma unroll
    for (int ks = 0; ks < 4; ++ks) {
        const int k0 = ks * 32 + hi * 8;
        half8 a[4], b[4];
        #pragma unroll
        for (int i = 0; i < 4; ++i) {
            int ra = wm * 64 + i * 16 + ln15;
            a[i] = *(const half8*)&asl[ra * 128 + (k0 ^ ((ra & 7) << 3))];
            int cb = wn * 64 + i * 16 + ln15;
            b[i] = *(const half8*)&wsl[cb * 128 + (k0 ^ ((cb & 7) << 3))];
        }
        #pragma unroll
        for (int i = 0; i < 4; ++i)
            #pragma unroll
            for (int j = 0; j < 4; ++j)
                acc[i][j] = __builtin_amdgcn_mfma_f32_16x16x32_f16(a[i], b[j], acc[i][j], 0, 0, 0);
    }

    #pragma unroll
    for (int i = 0; i < 4; ++i) {
        #pragma unroll
        for (int q = 0; q < 4; ++q) {
            int r = row0 + wm * 64 + i * 16 + hi * 4 + q;
            if (r < nrows) {
                float s = dinv[r];
                #pragma unroll
                for (int j = 0; j < 4; ++j) {
                    H[(size_t)r * HID + wn * 64 + j * 16 + ln15] =
                        (_Float16)(acc[i][j][q] * s);
                }
            }
        }
    }
}

// ---------------------------------------------------------------- fused agg+GEMM
// A[r] = relu(dinv[r] * sum_{src in N(r)} hprev[src] + bias)  (gathered, in-reg)
// H[r] = dinv[r] * (A[r] @ W)
// Wave w stages nodes w*32..w*32+31 via quarter-wave gather (es=lane>>4,
// fg=lane&15); after shfl fold, lane packs features fg*8+es*2(+1) into the
// swizzled LDS A-tile. MFMA body identical to k_gemm.
__global__ __launch_bounds__(256, 2) void k_gemm_agg(
    const _Float16* __restrict__ hprev, const int* __restrict__ csr_off,
    const int* __restrict__ rowptr, const float* __restrict__ dinv,
    const float* __restrict__ bias, const _Float16* __restrict__ WT,
    _Float16* __restrict__ H, int nrows)
{
    __shared__ _Float16 asl[128 * 128];   // 32 KB
    __shared__ _Float16 wsl[128 * 128];   // 32 KB
    __shared__ int s_ptr[129];
    const int tid  = threadIdx.x;
    const int lane = tid & 63;
    const int w    = tid >> 6;
    const int row0 = blockIdx.x * 128;

    if (tid < 129) {
        int n = row0 + tid; if (n > nrows) n = nrows;
        s_ptr[tid] = rowptr[n];
    }
    // stage W while s_ptr settles
    #pragma unroll
    for (int i = 0; i < 8; ++i) {
        int g = i * 256 + tid;
        int c = g >> 4, k8 = (g & 15) << 3;
        uint4 wv = *(const uint4*)(WT + c * 128 + k8);
        *(uint4*)&wsl[c * 128 + (k8 ^ ((c & 7) << 3))] = wv;
    }
    __syncthreads();

    const int es = lane >> 4;          // 0..3 edge slot (HIGH bits: quarter-wave row)
    const int fg = lane & 15;          // feature group
    const char* hb = (const char*)hprev;
    const int f0 = fg * 8 + es * 2;
    const float2 bv = *(const float2*)(bias + f0);
    const uint4 z = make_uint4(0, 0, 0, 0);

    #pragma unroll 2
    for (int t = 0; t < 32; ++t) {
        const int ni  = (w << 5) + t;
        const int beg = s_ptr[ni], end = s_ptr[ni + 1];

        float accf[8];
        #pragma unroll
        for (int j = 0; j < 8; ++j) accf[j] = 0.0f;

        int nr  = (end - beg + 3) >> 2;
        int idx = beg + es;
        int r   = 0;
        for (; r + 1 < nr; r += 2, idx += 8) {
            int o0 = (idx     < end) ? csr_off[idx]     : -1;
            int o1 = (idx + 4 < end) ? csr_off[idx + 4] : -1;
            uint4 u0 = (o0 >= 0) ? *(const uint4*)(hb + (size_t)(unsigned)o0 + fg * 16) : z;
            uint4 u1 = (o1 >= 0) ? *(const uint4*)(hb + (size_t)(unsigned)o1 + fg * 16) : z;
            H8 h0; h0.u = u0;
            H8 h1; h1.u = u1;
            acc8(h0, accf);
            acc8(h1, accf);
        }
        if (r < nr) {
            int o0 = (idx < end) ? csr_off[idx] : -1;
            uint4 u0 = (o0 >= 0) ? *(const uint4*)(hb + (size_t)(unsigned)o0 + fg * 16) : z;
            H8 h0; h0.u = u0;
            acc8(h0, accf);
        }

        #pragma unroll
        for (int j = 0; j < 8; ++j) {
            accf[j] += __shfl_xor(accf[j], 16);
            accf[j] += __shfl_xor(accf[j], 32);
        }

        float v0 = es < 2 ? (es == 0 ? accf[0] : accf[2])
                          : (es == 2 ? accf[4] : accf[6]);
        float v1 = es < 2 ? (es == 0 ? accf[1] : accf[3])
                          : (es == 2 ? accf[5] : accf[7]);
        int node = row0 + ni;
        float s = (node < nrows) ? dinv[node] : 0.0f;
        union { _Float16 h[2]; unsigned u; } o;
        o.h[0] = (_Float16)fmaxf(v0 * s + bv.x, 0.0f);
        o.h[1] = (_Float16)fmaxf(v1 * s + bv.y, 0.0f);
        // swizzled LDS write: group base fg*8 XOR'd by row, +es*2 within group
        *(unsigned*)&asl[ni * 128 + (((unsigned)(fg * 8)) ^ ((ni & 7) << 3)) + es * 2] = o.u;
    }
    __syncthreads();

    const int wm   = w >> 1, wn = w & 1;
    const int ln15 = lane & 15;
    const int hi   = lane >> 4;

    f32x4 acc[4][4];
    #pragma unroll
    for (int i = 0; i < 4; ++i)
        #pragma unroll
        for (int j = 0; j < 4; ++j) {
            acc[i][j][0] = 0.0f; acc[i][j][1] = 0.0f;
            acc[i][j][2] = 0.0f; acc[i][j][3] = 0.0f;
        }

    #pragma unroll
    for (int ks = 0; ks < 4; ++ks) {
        const int k0 = ks * 32 + hi * 8;
        half8 a[4], b[4];
        #pragma unroll
        for (int i = 0; i < 4; ++i) {
            int ra = wm * 64 + i * 16 + ln15;
            a[i] = *(const half8*)&asl[ra * 128 + (k0 ^ ((ra & 7) << 3))];
            int cb = wn * 64 + i * 16 + ln15;
            b[i] = *(const half8*)&wsl[cb * 128 + (k0 ^ ((cb & 7) << 3))];
        }
        #pragma unroll
        for (int i = 0; i < 4; ++i)
            #pragma unroll
            for (int j = 0; j < 4; ++j)
                acc[i][j] = __builtin_amdgcn_mfma_f32_16x16x32_f16(a[i], b[j], acc[i][j], 0, 0, 0);
    }

    #pragma unroll
    for (int i = 0; i < 4; ++i) {
        #pragma unroll
        for (int q = 0; q < 4; ++q) {
            int r = row0 + wm * 64 + i * 16 + hi * 4 + q;
            if (r < nrows) {
                float s = dinv[r];
                #pragma unroll
                for (int j = 0; j < 4; ++j) {
                    H[(size_t)r * HID + wn * 64 + j * 16 + ln15] =
                        (_Float16)(acc[i][j][q] * s);
                }
            }
        }
    }
}

// ---------------------------------------------------------------- final aggregate
// out[node] (f32) = dinv[node] * sum(hprev[src]) + b3   (R9 structure, proven)
__global__ __launch_bounds__(256) void k_aggregate_f(
    const _Float16* __restrict__ hs, const int* __restrict__ csr_off,
    const int* __restrict__ rowptr, const float* __restrict__ dinv,
    const float* __restrict__ bias, float* __restrict__ out, int N)
{
    constexpr int NB = 32;
    constexpr int CAP = 2048;
    __shared__ int s_off[CAP + 8];
    __shared__ int s_ptr[NB + 1];

    const int tid = threadIdx.x;
    const int n0  = blockIdx.x * NB;   // 3125 * 32 == 100000 exactly
    if (tid <= NB) s_ptr[tid] = rowptr[n0 + tid];
    __syncthreads();
    const int Rbeg = s_ptr[0];
    const int cnt  = s_ptr[NB] - Rbeg;
    const bool fast = cnt <= CAP;
    if (fast) {
        for (int i = tid; i < cnt; i += 256) s_off[i] = csr_off[Rbeg + i];
    }
    __syncthreads();
    const int* offp = fast ? (const int*)s_off : (csr_off + Rbeg);

    const int lane = tid & 63;
    const int w    = tid >> 6;
    const int es   = lane >> 4;
    const int fg   = lane & 15;
    const char* hb = (const char*)hs;
    const int f0   = fg * 8 + es * 2;
    const float2 bv = *(const float2*)(bias + f0);
    const uint4 z = make_uint4(0, 0, 0, 0);

    #pragma unroll 2
    for (int t = 0; t < 8; ++t) {
        const int ni   = (w << 3) + t;
        const int node = n0 + ni;
        const int beg  = s_ptr[ni] - Rbeg;
        const int end  = s_ptr[ni + 1] - Rbeg;

        float accf[8];
        #pragma unroll
        for (int j = 0; j < 8; ++j) accf[j] = 0.0f;

        int nr  = (end - beg + 3) >> 2;
        int idx = beg + es;
        int r   = 0;
        for (; r + 1 < nr; r += 2, idx += 8) {
            int o0 = (idx     < end) ? offp[idx]     : -1;
            int o1 = (idx + 4 < end) ? offp[idx + 4] : -1;
            uint4 u0 = (o0 >= 0) ? *(const uint4*)(hb + (size_t)(unsigned)o0 + fg * 16) : z;
            uint4 u1 = (o1 >= 0) ? *(const uint4*)(hb + (size_t)(unsigned)o1 + fg * 16) : z;
            H8 h0; h0.u = u0;
            H8 h1; h1.u = u1;
            acc8(h0, accf);
            acc8(h1, accf);
        }
        if (r < nr) {
            int o0 = (idx < end) ? offp[idx] : -1;
            uint4 u0 = (o0 >= 0) ? *(const uint4*)(hb + (size_t)(unsigned)o0 + fg * 16) : z;
            H8 h0; h0.u = u0;
            acc8(h0, accf);
        }

        #pragma unroll
        for (int j = 0; j < 8; ++j) {
            accf[j] += __shfl_xor(accf[j], 16);
            accf[j] += __shfl_xor(accf[j], 32);
        }

        float v0 = es < 2 ? (es == 0 ? accf[0] : accf[2])
                          : (es == 2 ? accf[4] : accf[6]);
        float v1 = es < 2 ? (es == 0 ? accf[1] : accf[3])
                          : (es == 2 ? accf[5] : accf[7]);
        float s = dinv[node];
        v0 = v0 * s + bv.x;
        v1 = v1 * s + bv.y;
        *(float2*)(out + (size_t)node * HID + f0) = make_float2(v0, v1);
    }
}

// ---------------------------------------------------------------- launch
extern "C" void kernel_launch(void* const* d_in, const int* in_sizes, int n_in,
                              void* d_out, int out_size, void* d_ws, size_t ws_size,
                              hipStream_t stream)
{
    const float* x  = (const float*)d_in[0];
    const float* W1 = (const float*)d_in[1];
    const float* b1 = (const float*)d_in[2];
    const float* W2 = (const float*)d_in[3];
    const float* b2 = (const float*)d_in[4];
    const float* W3 = (const float*)d_in[5];
    const float* b3 = (const float*)d_in[6];
    const int*   ei = (const int*)d_in[7];
    const int* row  = ei;            // sources
    const int* colv = ei + NE;       // targets
    float* out = (float*)d_out;

    _Float16* hA  = (_Float16*)d_ws;                  // NN*HID
    _Float16* hB  = hA + (size_t)NN * HID;            // NN*HID
    _Float16* wt  = hB + (size_t)NN * HID;            // 3*128*128
    int*   degi    = (int*)(wt + 3 * 128 * 128);      // NN
    float* dinv    = (float*)(degi + NN);             // NN
    int*   rowptr  = (int*)(dinv + NN);               // NN+1
    int*   cursor  = rowptr + NN + 1;                 // NN
    int*   bsum    = cursor + NN;                     // 512
    int*   csr_off = bsum + 512;                      // NE

    const int TB = 256;
    const int nScanBlocks = (NN + 255) / 256;         // 391

    k_wprep<<<384, 128, 0, stream>>>(W1, W2, W3, wt);
    hipMemsetAsync(degi, 0, NN * sizeof(int), stream);
    k_degi      <<<(NE + TB - 1) / TB, TB, 0, stream>>>(colv, degi, NE);
    k_blocksum  <<<nScanBlocks, 256, 0, stream>>>(degi, dinv, bsum, NN);
    k_scan_bsum <<<1, 512, 0, stream>>>(bsum, nScanBlocks);
    k_scan_apply<<<nScanBlocks, 256, 0, stream>>>(degi, bsum, rowptr, cursor, NN);
    k_fill_csr  <<<(NE + TB - 1) / TB, TB, 0, stream>>>(row, colv, cursor, csr_off, NE);

    const int gemmBlocks = (NN + 127) / 128;          // 782
    const int aggBlocks  = (NN + 31) / 32;            // 3125

    // layer 1: hA = dinv*(x@W1)
    k_gemm<<<gemmBlocks, TB, 0, stream>>>(x, wt, dinv, hA, NN);
    // layer 2 fused: A = relu(agg(hA)+b1); hB = dinv*(A@W2)
    k_gemm_agg<<<gemmBlocks, TB, 0, stream>>>(hA, csr_off, rowptr, dinv, b1,
                                              wt + (1 << 14), hB, NN);
    // layer 3 fused: A = relu(agg(hB)+b2); hA = dinv*(A@W3)
    k_gemm_agg<<<gemmBlocks, TB, 0, stream>>>(hB, csr_off, rowptr, dinv, b2,
                                              wt + (2 << 14), hA, NN);
    // final: out = agg(hA) + b3
    k_aggregate_f<<<aggBlocks, TB, 0, stream>>>(hA, csr_off, rowptr, dinv, b3, out, NN);
}

// Round 11
// 248.008 us; speedup vs baseline: 1.3053x; 1.3053x over previous
//
#include <hip/hip_runtime.h>
#include <cstddef>

#define NN 100000
#define NE 600000
#define HID 128

typedef _Float16 half8 __attribute__((ext_vector_type(8)));
typedef _Float16 half2v __attribute__((ext_vector_type(2)));
typedef float f32x4 __attribute__((ext_vector_type(4)));

union H8 { _Float16 h[8]; half2v p[4]; uint4 u; half8 v; };

// shared accumulate helper: accf[0..7] += 8 f16 lanes of hh
__device__ __forceinline__ void acc8(const H8& hh, float* accf) {
#if __has_builtin(__builtin_amdgcn_fdot2)
    const half2v selx = {(_Float16)1.0f, (_Float16)0.0f};
    const half2v sely = {(_Float16)0.0f, (_Float16)1.0f};
    #pragma unroll
    for (int p = 0; p < 4; ++p) {
        accf[2*p]   = __builtin_amdgcn_fdot2(hh.p[p], selx, accf[2*p],   false);
        accf[2*p+1] = __builtin_amdgcn_fdot2(hh.p[p], sely, accf[2*p+1], false);
    }
#else
    #pragma unroll
    for (int j = 0; j < 8; ++j) accf[j] += (float)hh.h[j];
#endif
}

// ---------------------------------------------------------------- degree (int)
__global__ void k_degi(const int* __restrict__ col, int* __restrict__ degi, int E) {
    int e = blockIdx.x * blockDim.x + threadIdx.x;
    if (e < E) atomicAdd(&degi[col[e]], 1);
}

// ---------------------------------------------------------------- W -> WT f16
__global__ void k_wprep(const float* __restrict__ W1, const float* __restrict__ W2,
                        const float* __restrict__ W3, _Float16* __restrict__ wt) {
    int b = blockIdx.x;            // 0..383
    int layer = b >> 7, k = b & 127;
    const float* W = layer == 0 ? W1 : (layer == 1 ? W2 : W3);
    int c = threadIdx.x;           // 0..127
    wt[((size_t)layer << 14) + c * 128 + k] = (_Float16)W[k * 128 + c];
}

// ---------------------------------------------------------------- prefix scan
__global__ void k_blocksum(const int* __restrict__ degi, float* __restrict__ dinv,
                           int* __restrict__ bsum, int N) {
    __shared__ int sh[256];
    int i = blockIdx.x * 256 + threadIdx.x;
    int v = i < N ? degi[i] : 0;
    if (i < N) dinv[i] = v > 0 ? rsqrtf((float)v) : 0.0f;
    sh[threadIdx.x] = v;
    __syncthreads();
    for (int s = 128; s > 0; s >>= 1) {
        if (threadIdx.x < s) sh[threadIdx.x] += sh[threadIdx.x + s];
        __syncthreads();
    }
    if (threadIdx.x == 0) bsum[blockIdx.x] = sh[0];
}

__global__ void k_scan_bsum(int* __restrict__ bsum, int nb) {
    __shared__ int sh[512];
    int tid = threadIdx.x;
    int v = (tid < nb) ? bsum[tid] : 0;
    sh[tid] = v;
    __syncthreads();
    #pragma unroll
    for (int s = 1; s < 512; s <<= 1) {
        int t = (tid >= s) ? sh[tid - s] : 0;
        __syncthreads();
        sh[tid] += t;
        __syncthreads();
    }
    if (tid < nb) bsum[tid] = sh[tid] - v;   // exclusive
}

__global__ void k_scan_apply(const int* __restrict__ degi, const int* __restrict__ bsum,
                             int* __restrict__ rowptr, int* __restrict__ cursor, int N) {
    __shared__ int sh[256];
    int i = blockIdx.x * 256 + threadIdx.x;
    int v = (i < N) ? degi[i] : 0;
    sh[threadIdx.x] = v;
    __syncthreads();
    #pragma unroll
    for (int s = 1; s < 256; s <<= 1) {
        int t = (threadIdx.x >= s) ? sh[threadIdx.x - s] : 0;
        __syncthreads();
        sh[threadIdx.x] += t;
        __syncthreads();
    }
    if (i < N) {
        int excl = bsum[blockIdx.x] + sh[threadIdx.x] - v;
        rowptr[i] = excl;
        cursor[i] = excl;
        if (i == N - 1) rowptr[N] = bsum[blockIdx.x] + sh[threadIdx.x];
    }
}

// csr_off stores BYTE offset of the source row (src * HID * 2, fits int32)
__global__ void k_fill_csr(const int* __restrict__ row, const int* __restrict__ col,
                           int* __restrict__ cursor, int* __restrict__ csr_off, int E) {
    int e = blockIdx.x * blockDim.x + threadIdx.x;
    if (e >= E) return;
    int r = row[e], c = col[e];
    int pos = atomicAdd(&cursor[c], 1);
    csr_off[pos] = r * (HID * 2);
}

// ---------------------------------------------------------------- MFMA GEMM (layer 1)
// H[r] (f16) = dinv[r] * (A[r] @ W)
__global__ __launch_bounds__(256, 2) void k_gemm(
    const float* __restrict__ A, const _Float16* __restrict__ WT,
    const float* __restrict__ dinv, _Float16* __restrict__ H, int nrows)
{
    __shared__ _Float16 asl[128 * 128];   // 32 KB
    __shared__ _Float16 wsl[128 * 128];   // 32 KB
    const int tid  = threadIdx.x;
    const int lane = tid & 63;
    const int w    = tid >> 6;
    const int wm   = w >> 1, wn = w & 1;
    const int ln15 = lane & 15;
    const int hi   = lane >> 4;           // 0..3
    const int row0 = blockIdx.x * 128;

    #pragma unroll
    for (int i = 0; i < 8; ++i) {
        int g = i * 256 + tid;
        int c = g >> 4, k8 = (g & 15) << 3;
        uint4 wv = *(const uint4*)(WT + c * 128 + k8);
        *(uint4*)&wsl[c * 128 + (k8 ^ ((c & 7) << 3))] = wv;
    }
    #pragma unroll
    for (int i = 0; i < 8; ++i) {
        int g = i * 256 + tid;
        int r = g >> 4, c8 = (g & 15) << 3;
        int gr = row0 + r; if (gr >= nrows) gr = nrows - 1;
        const float4* src = (const float4*)(A + (size_t)gr * HID + c8);
        float4 v0 = src[0], v1 = src[1];
        H8 o;
        o.h[0] = (_Float16)v0.x; o.h[1] = (_Float16)v0.y;
        o.h[2] = (_Float16)v0.z; o.h[3] = (_Float16)v0.w;
        o.h[4] = (_Float16)v1.x; o.h[5] = (_Float16)v1.y;
        o.h[6] = (_Float16)v1.z; o.h[7] = (_Float16)v1.w;
        *(uint4*)&asl[r * 128 + (c8 ^ ((r & 7) << 3))] = o.u;
    }
    __syncthreads();

    f32x4 acc[4][4];
    #pragma unroll
    for (int i = 0; i < 4; ++i)
        #pragma unroll
        for (int j = 0; j < 4; ++j) {
            acc[i][j][0] = 0.0f; acc[i][j][1] = 0.0f;
            acc[i][j][2] = 0.0f; acc[i][j][3] = 0.0f;
        }

    #pragma unroll
    for (int ks = 0; ks < 4; ++ks) {
        const int k0 = ks * 32 + hi * 8;
        half8 a[4], b[4];
        #pragma unroll
        for (int i = 0; i < 4; ++i) {
            int ra = wm * 64 + i * 16 + ln15;
            a[i] = *(const half8*)&asl[ra * 128 + (k0 ^ ((ra & 7) << 3))];
            int cb = wn * 64 + i * 16 + ln15;
            b[i] = *(const half8*)&wsl[cb * 128 + (k0 ^ ((cb & 7) << 3))];
        }
        #pragma unroll
        for (int i = 0; i < 4; ++i)
            #pragma unroll
            for (int j = 0; j < 4; ++j)
                acc[i][j] = __builtin_amdgcn_mfma_f32_16x16x32_f16(a[i], b[j], acc[i][j], 0, 0, 0);
    }

    #pragma unroll
    for (int i = 0; i < 4; ++i) {
        #pragma unroll
        for (int q = 0; q < 4; ++q) {
            int r = row0 + wm * 64 + i * 16 + hi * 4 + q;
            if (r < nrows) {
                float s = dinv[r];
                #pragma unroll
                for (int j = 0; j < 4; ++j) {
                    H[(size_t)r * HID + wn * 64 + j * 16 + ln15] =
                        (_Float16)(acc[i][j][q] * s);
                }
            }
        }
    }
}

// ---------------------------------------------------------------- fused agg+GEMM (512 thr)
// A[r] = relu(dinv[r] * sum_{src in N(r)} hprev[src] + bias)  (gathered, in-reg)
// H[r] = dinv[r] * (A[r] @ W)
// 512 threads = 8 waves; wave w stages nodes w*16..w*16+15 (quarter-wave gather,
// es=lane>>4, fg=lane&15), packs into swizzled LDS A-tile. MFMA: wave ->
// 32x64 quadrant (wm=w>>1 row-quad, wn=w&1 col-half).
__global__ __launch_bounds__(512, 2) void k_gemm_agg(
    const _Float16* __restrict__ hprev, const int* __restrict__ csr_off,
    const int* __restrict__ rowptr, const float* __restrict__ dinv,
    const float* __restrict__ bias, const _Float16* __restrict__ WT,
    _Float16* __restrict__ H, int nrows)
{
    __shared__ _Float16 asl[128 * 128];   // 32 KB
    __shared__ _Float16 wsl[128 * 128];   // 32 KB
    __shared__ int s_ptr[129];
    const int tid  = threadIdx.x;
    const int lane = tid & 63;
    const int w    = tid >> 6;            // 0..7
    const int row0 = blockIdx.x * 128;

    if (tid < 129) {
        int n = row0 + tid; if (n > nrows) n = nrows;
        s_ptr[tid] = rowptr[n];
    }
    // stage W while s_ptr settles: 2048 uint4, 4/thread
    #pragma unroll
    for (int i = 0; i < 4; ++i) {
        int g = i * 512 + tid;
        int c = g >> 4, k8 = (g & 15) << 3;
        uint4 wv = *(const uint4*)(WT + c * 128 + k8);
        *(uint4*)&wsl[c * 128 + (k8 ^ ((c & 7) << 3))] = wv;
    }
    __syncthreads();

    const int es = lane >> 4;          // 0..3 edge slot (HIGH bits: quarter-wave row)
    const int fg = lane & 15;          // feature group
    const char* hb = (const char*)hprev;
    const int f0 = fg * 8 + es * 2;
    const float2 bv = *(const float2*)(bias + f0);
    const uint4 z = make_uint4(0, 0, 0, 0);

    #pragma unroll 2
    for (int t = 0; t < 16; ++t) {
        const int ni  = (w << 4) + t;
        const int beg = s_ptr[ni], end = s_ptr[ni + 1];

        float accf[8];
        #pragma unroll
        for (int j = 0; j < 8; ++j) accf[j] = 0.0f;

        int nr  = (end - beg + 3) >> 2;
        int idx = beg + es;
        int r   = 0;
        for (; r + 1 < nr; r += 2, idx += 8) {
            int o0 = (idx     < end) ? csr_off[idx]     : -1;
            int o1 = (idx + 4 < end) ? csr_off[idx + 4] : -1;
            uint4 u0 = (o0 >= 0) ? *(const uint4*)(hb + (size_t)(unsigned)o0 + fg * 16) : z;
            uint4 u1 = (o1 >= 0) ? *(const uint4*)(hb + (size_t)(unsigned)o1 + fg * 16) : z;
            H8 h0; h0.u = u0;
            H8 h1; h1.u = u1;
            acc8(h0, accf);
            acc8(h1, accf);
        }
        if (r < nr) {
            int o0 = (idx < end) ? csr_off[idx] : -1;
            uint4 u0 = (o0 >= 0) ? *(const uint4*)(hb + (size_t)(unsigned)o0 + fg * 16) : z;
            H8 h0; h0.u = u0;
            acc8(h0, accf);
        }

        #pragma unroll
        for (int j = 0; j < 8; ++j) {
            accf[j] += __shfl_xor(accf[j], 16);
            accf[j] += __shfl_xor(accf[j], 32);
        }

        float v0 = es < 2 ? (es == 0 ? accf[0] : accf[2])
                          : (es == 2 ? accf[4] : accf[6]);
        float v1 = es < 2 ? (es == 0 ? accf[1] : accf[3])
                          : (es == 2 ? accf[5] : accf[7]);
        int node = row0 + ni;
        float s = (node < nrows) ? dinv[node] : 0.0f;
        union { _Float16 h[2]; unsigned u; } o;
        o.h[0] = (_Float16)fmaxf(v0 * s + bv.x, 0.0f);
        o.h[1] = (_Float16)fmaxf(v1 * s + bv.y, 0.0f);
        // swizzled LDS write: group base fg*8 XOR'd by row, +es*2 within group
        *(unsigned*)&asl[ni * 128 + (((unsigned)(fg * 8)) ^ ((ni & 7) << 3)) + es * 2] = o.u;
    }
    __syncthreads();

    // MFMA: wave w -> rows [wm*32, wm*32+32), cols [wn*64, wn*64+64)
    const int wm   = w >> 1, wn = w & 1;
    const int ln15 = lane & 15;
    const int hi   = lane >> 4;

    f32x4 acc[2][4];
    #pragma unroll
    for (int i = 0; i < 2; ++i)
        #pragma unroll
        for (int j = 0; j < 4; ++j) {
            acc[i][j][0] = 0.0f; acc[i][j][1] = 0.0f;
            acc[i][j][2] = 0.0f; acc[i][j][3] = 0.0f;
        }

    #pragma unroll
    for (int ks = 0; ks < 4; ++ks) {
        const int k0 = ks * 32 + hi * 8;
        half8 a[2], b[4];
        #pragma unroll
        for (int i = 0; i < 2; ++i) {
            int ra = wm * 32 + i * 16 + ln15;
            a[i] = *(const half8*)&asl[ra * 128 + (k0 ^ ((ra & 7) << 3))];
        }
        #pragma unroll
        for (int j = 0; j < 4; ++j) {
            int cb = wn * 64 + j * 16 + ln15;
            b[j] = *(const half8*)&wsl[cb * 128 + (k0 ^ ((cb & 7) << 3))];
        }
        #pragma unroll
        for (int i = 0; i < 2; ++i)
            #pragma unroll
            for (int j = 0; j < 4; ++j)
                acc[i][j] = __builtin_amdgcn_mfma_f32_16x16x32_f16(a[i], b[j], acc[i][j], 0, 0, 0);
    }

    #pragma unroll
    for (int i = 0; i < 2; ++i) {
        #pragma unroll
        for (int q = 0; q < 4; ++q) {
            int r = row0 + wm * 32 + i * 16 + hi * 4 + q;
            if (r < nrows) {
                float s = dinv[r];
                #pragma unroll
                for (int j = 0; j < 4; ++j) {
                    H[(size_t)r * HID + wn * 64 + j * 16 + ln15] =
                        (_Float16)(acc[i][j][q] * s);
                }
            }
        }
    }
}

// ---------------------------------------------------------------- final aggregate
// out[node] (f32) = dinv[node] * sum(hprev[src]) + b3   (R9 structure, proven)
__global__ __launch_bounds__(256) void k_aggregate_f(
    const _Float16* __restrict__ hs, const int* __restrict__ csr_off,
    const int* __restrict__ rowptr, const float* __restrict__ dinv,
    const float* __restrict__ bias, float* __restrict__ out, int N)
{
    constexpr int NB = 32;
    constexpr int CAP = 2048;
    __shared__ int s_off[CAP + 8];
    __shared__ int s_ptr[NB + 1];

    const int tid = threadIdx.x;
    const int n0  = blockIdx.x * NB;   // 3125 * 32 == 100000 exactly
    if (tid <= NB) s_ptr[tid] = rowptr[n0 + tid];
    __syncthreads();
    const int Rbeg = s_ptr[0];
    const int cnt  = s_ptr[NB] - Rbeg;
    const bool fast = cnt <= CAP;
    if (fast) {
        for (int i = tid; i < cnt; i += 256) s_off[i] = csr_off[Rbeg + i];
    }
    __syncthreads();
    const int* offp = fast ? (const int*)s_off : (csr_off + Rbeg);

    const int lane = tid & 63;
    const int w    = tid >> 6;
    const int es   = lane >> 4;
    const int fg   = lane & 15;
    const char* hb = (const char*)hs;
    const int f0   = fg * 8 + es * 2;
    const float2 bv = *(const float2*)(bias + f0);
    const uint4 z = make_uint4(0, 0, 0, 0);

    #pragma unroll 2
    for (int t = 0; t < 8; ++t) {
        const int ni   = (w << 3) + t;
        const int node = n0 + ni;
        const int beg  = s_ptr[ni] - Rbeg;
        const int end  = s_ptr[ni + 1] - Rbeg;

        float accf[8];
        #pragma unroll
        for (int j = 0; j < 8; ++j) accf[j] = 0.0f;

        int nr  = (end - beg + 3) >> 2;
        int idx = beg + es;
        int r   = 0;
        for (; r + 1 < nr; r += 2, idx += 8) {
            int o0 = (idx     < end) ? offp[idx]     : -1;
            int o1 = (idx + 4 < end) ? offp[idx + 4] : -1;
            uint4 u0 = (o0 >= 0) ? *(const uint4*)(hb + (size_t)(unsigned)o0 + fg * 16) : z;
            uint4 u1 = (o1 >= 0) ? *(const uint4*)(hb + (size_t)(unsigned)o1 + fg * 16) : z;
            H8 h0; h0.u = u0;
            H8 h1; h1.u = u1;
            acc8(h0, accf);
            acc8(h1, accf);
        }
        if (r < nr) {
            int o0 = (idx < end) ? offp[idx] : -1;
            uint4 u0 = (o0 >= 0) ? *(const uint4*)(hb + (size_t)(unsigned)o0 + fg * 16) : z;
            H8 h0; h0.u = u0;
            acc8(h0, accf);
        }

        #pragma unroll
        for (int j = 0; j < 8; ++j) {
            accf[j] += __shfl_xor(accf[j], 16);
            accf[j] += __shfl_xor(accf[j], 32);
        }

        float v0 = es < 2 ? (es == 0 ? accf[0] : accf[2])
                          : (es == 2 ? accf[4] : accf[6]);
        float v1 = es < 2 ? (es == 0 ? accf[1] : accf[3])
                          : (es == 2 ? accf[5] : accf[7]);
        float s = dinv[node];
        v0 = v0 * s + bv.x;
        v1 = v1 * s + bv.y;
        *(float2*)(out + (size_t)node * HID + f0) = make_float2(v0, v1);
    }
}

// ---------------------------------------------------------------- launch
extern "C" void kernel_launch(void* const* d_in, const int* in_sizes, int n_in,
                              void* d_out, int out_size, void* d_ws, size_t ws_size,
                              hipStream_t stream)
{
    const float* x  = (const float*)d_in[0];
    const float* W1 = (const float*)d_in[1];
    const float* b1 = (const float*)d_in[2];
    const float* W2 = (const float*)d_in[3];
    const float* b2 = (const float*)d_in[4];
    const float* W3 = (const float*)d_in[5];
    const float* b3 = (const float*)d_in[6];
    const int*   ei = (const int*)d_in[7];
    const int* row  = ei;            // sources
    const int* colv = ei + NE;       // targets
    float* out = (float*)d_out;

    _Float16* hA  = (_Float16*)d_ws;                  // NN*HID
    _Float16* hB  = hA + (size_t)NN * HID;            // NN*HID
    _Float16* wt  = hB + (size_t)NN * HID;            // 3*128*128
    int*   degi    = (int*)(wt + 3 * 128 * 128);      // NN
    float* dinv    = (float*)(degi + NN);             // NN
    int*   rowptr  = (int*)(dinv + NN);               // NN+1
    int*   cursor  = rowptr + NN + 1;                 // NN
    int*   bsum    = cursor + NN;                     // 512
    int*   csr_off = bsum + 512;                      // NE

    const int TB = 256;
    const int nScanBlocks = (NN + 255) / 256;         // 391

    k_wprep<<<384, 128, 0, stream>>>(W1, W2, W3, wt);
    hipMemsetAsync(degi, 0, NN * sizeof(int), stream);
    k_degi      <<<(NE + TB - 1) / TB, TB, 0, stream>>>(colv, degi, NE);
    k_blocksum  <<<nScanBlocks, 256, 0, stream>>>(degi, dinv, bsum, NN);
    k_scan_bsum <<<1, 512, 0, stream>>>(bsum, nScanBlocks);
    k_scan_apply<<<nScanBlocks, 256, 0, stream>>>(degi, bsum, rowptr, cursor, NN);
    k_fill_csr  <<<(NE + TB - 1) / TB, TB, 0, stream>>>(row, colv, cursor, csr_off, NE);

    const int gemmBlocks = (NN + 127) / 128;          // 782
    const int aggBlocks  = (NN + 31) / 32;            // 3125

    // layer 1: hA = dinv*(x@W1)
    k_gemm<<<gemmBlocks, TB, 0, stream>>>(x, wt, dinv, hA, NN);
    // layer 2 fused: A = relu(agg(hA)+b1); hB = dinv*(A@W2)
    k_gemm_agg<<<gemmBlocks, 512, 0, stream>>>(hA, csr_off, rowptr, dinv, b1,
                                               wt + (1 << 14), hB, NN);
    // layer 3 fused: A = relu(agg(hB)+b2); hA = dinv*(A@W3)
    k_gemm_agg<<<gemmBlocks, 512, 0, stream>>>(hB, csr_off, rowptr, dinv, b2,
                                               wt + (2 << 14), hA, NN);
    // final: out = agg(hA) + b3
    k_aggregate_f<<<aggBlocks, TB, 0, stream>>>(hA, csr_off, rowptr, dinv, b3, out, NN);
}